// Round 8
// baseline (1291.089 us; speedup 1.0000x reference)
//
#include <hip/hip_runtime.h>
#include <math.h>

#define B 32
#define T 32
#define O_DIM 256
#define H_DIM 512
#define HS 64
#define MS 2048
#define NCOL 516
#define NCH 32          // 64-row softmax chunks

typedef __attribute__((ext_vector_type(4))) float f4;

__device__ __forceinline__ float sigm(float x){ return 1.0f/(1.0f+__expf(-x)); }
__device__ __forceinline__ float hsum(f4 v){ return (v.x + v.y) + (v.z + v.w); }

// ---------------- prep kernels ----------------
__global__ __launch_bounds__(256) void k_transpose_t(float* __restrict__ dst,
                                                     const float* __restrict__ src,
                                                     int N, int K){
  __shared__ float tile[32][33];
  int jb = blockIdx.x*32, kb = blockIdx.y*32;
  int tj = threadIdx.x & 31, tk = threadIdx.x >> 5;
  #pragma unroll
  for (int p = 0; p < 4; ++p){
    int j = jb + tk + p*8, k = kb + tj;
    if (j < N && k < K) tile[tk + p*8][tj] = src[j*K + k];
  }
  __syncthreads();
  #pragma unroll
  for (int p = 0; p < 4; ++p){
    int k = kb + tk + p*8, j = jb + tj;
    if (j < N && k < K) dst[k*N + j] = tile[tj][tk + p*8];
  }
}

__global__ __launch_bounds__(256) void k_ghead(float* __restrict__ dst,
                                               const float* __restrict__ W_head){
  int idx = blockIdx.x*256 + threadIdx.x;     // col*512 + k
  if (idx >= 520*512) return;
  int col = idx >> 9, k = idx & 511;
  float v = 0.f;
  if (col < NCOL){ int n = col/129, c = col%129; v = W_head[((size_t)n*2115 + c)*512 + k]; }
  dst[idx] = v;
}

__global__ __launch_bounds__(256) void k_xt(f4* __restrict__ XT4,
                                            const float* __restrict__ x){
  int idx = blockIdx.x*256 + threadIdx.x;     // t*2048 + k4*32 + b
  int b = idx & 31, k4 = (idx >> 5) & 63, t = idx >> 11;
  XT4[idx] = ((const f4*)x)[(size_t)(b*T + t)*64 + k4];
}

// ---------------- PH_A: gates GEMM + LSTM (256 blocks x 512 thr) ----------------
// k-split: waves 0-3 (khalf=0) do x+read half; waves 4-7 (khalf=1) do h half.
__global__ __launch_bounds__(512) void k_A(
    const f4* __restrict__ XT4, const float* __restrict__ W_ih,
    const float* __restrict__ W_hh, const float* __restrict__ b_ih,
    const float* __restrict__ b_hh, const f4* __restrict__ READT4,
    float* __restrict__ HHT, float* __restrict__ CF, int t)
{
  __shared__ f4 WS[8*256];         // 8 rows x (128 f4 W_ih + 128 f4 W_hh) = 32 KB
  __shared__ float glp[2][8][33];  // per-khalf partials
  const int bid = blockIdx.x, tid = threadIdx.x;
  const f4* HHT4 = (const f4*)HHT;
  for (int idx = tid; idx < 2048; idx += 512){
    int rsub = idx >> 8, q = idx & 255;
    int gate = rsub & 3, jj = (rsub >> 2) & 1;
    int row = gate*512 + bid*2 + jj;
    WS[idx] = (q < 128) ? ((const f4*)W_ih)[(size_t)row*128 + q]
                        : ((const f4*)W_hh)[(size_t)row*128 + (q - 128)];
  }
  __syncthreads();
  {
    int b = tid & 31, rsub = (tid >> 5) & 7, khalf = tid >> 8;
    const f4* w = WS + rsub*256;
    f4 a0 = {0.f,0.f,0.f,0.f}, a1 = {0.f,0.f,0.f,0.f};
    if (khalf == 0){
      const f4* xt4 = XT4 + (size_t)t*2048;
      #pragma unroll 4
      for (int k4 = 0; k4 < 64; k4 += 2){
        a0 += w[k4]     * xt4[k4*32 + b];
        a1 += w[k4+1]   * xt4[(k4+1)*32 + b];
      }
      #pragma unroll 4
      for (int k4 = 0; k4 < 64; k4 += 2){
        a0 += w[64+k4]   * READT4[k4*32 + b];
        a1 += w[64+k4+1] * READT4[(k4+1)*32 + b];
      }
    } else if (t > 0){
      const f4* ht4 = HHT4 + (size_t)(t-1)*4096;
      #pragma unroll 4
      for (int k4 = 0; k4 < 128; k4 += 2){
        a0 += w[128+k4]   * ht4[k4*32 + b];
        a1 += w[128+k4+1] * ht4[(k4+1)*32 + b];
      }
    }
    glp[khalf][rsub][b] = hsum(a0 + a1);
  }
  __syncthreads();
  if (tid < 64){
    int b2 = tid & 31, jj2 = tid >> 5;
    int j2 = bid*2 + jj2;
    int r0 = 0*512 + j2, r1 = 1*512 + j2, r2 = 2*512 + j2, r3 = 3*512 + j2;
    float gi = glp[0][jj2*4+0][b2] + glp[1][jj2*4+0][b2] + b_ih[r0] + b_hh[r0];
    float gf = glp[0][jj2*4+1][b2] + glp[1][jj2*4+1][b2] + b_ih[r1] + b_hh[r1];
    float gg = glp[0][jj2*4+2][b2] + glp[1][jj2*4+2][b2] + b_ih[r2] + b_hh[r2];
    float go = glp[0][jj2*4+3][b2] + glp[1][jj2*4+3][b2] + b_ih[r3] + b_hh[r3];
    float c = sigm(gf)*CF[b2*512+j2] + sigm(gi)*tanhf(gg);
    float h = sigm(go)*tanhf(c);
    CF[b2*512+j2] = c;
    HHT[((size_t)t*128 + (j2>>2))*128 + b2*4 + (j2&3)] = h;
  }
}

// ---------------- PH_B: head projection (260 blocks, 2 cols, 4-way k-split) ----
__global__ __launch_bounds__(256) void k_B(
    const float* __restrict__ HHT, const float* __restrict__ WT_HD2,
    const float* __restrict__ b_head, float* __restrict__ HPT, int t)
{
  __shared__ float red[256];
  const int bid = blockIdx.x, tid = threadIdx.x;
  const f4* HHT4 = (const f4*)HHT;
  int b = tid & 31, cs = (tid>>5)&1, kq = tid>>6;   // kq in 0..3
  int col = bid*2 + cs;
  const f4* hT4 = HHT4 + (size_t)t*4096 + kq*1024;  // quarter of k (32 f4)
  const f4* w4  = (const f4*)(WT_HD2 + (size_t)col*512) + kq*32;
  f4 acc4 = {0.f, 0.f, 0.f, 0.f};
  #pragma unroll 4
  for (int k4 = 0; k4 < 32; ++k4)
    acc4 += w4[k4] * hT4[k4*32 + b];
  red[tid] = hsum(acc4);
  __syncthreads();
  if (kq == 0){
    float v = red[tid] + red[tid + 64] + red[tid + 128] + red[tid + 192];
    if (col < NCOL){ int n = col/129, c = col%129; v += b_head[n*2115 + c]; }
    HPT[col*32 + b] = v;
  }
}

// ---- PH_CDD: deferred mem-update + scores + wave-softmax + partial reads,
//      512 thr (chunk-pairs per half, as R6/R7) + last-arriver Dlite tail. ----
__global__ __launch_bounds__(512) void k_CDD(
    float* __restrict__ MEM, const float* __restrict__ HPT,
    float* __restrict__ SW, float* __restrict__ PART, float* __restrict__ PREAD,
    float* __restrict__ WST, float* __restrict__ WKS,
    float* __restrict__ READT, float* __restrict__ RHIST,
    const float* __restrict__ HHT, float* __restrict__ HF,
    unsigned* __restrict__ DCNT, int t)
{
  __shared__ float keys[8][64];
  __shared__ float mc[2][64][68];
  __shared__ float sc[2][4][64];
  __shared__ float ew[2][4][64];
  __shared__ f4 wkp[4][16];
  __shared__ float gmp[4], facp[4];
  __shared__ float gm2[4], dn2[4];
  __shared__ int lastf;
  const int bid = blockIdx.x, tid = threadIdx.x;
  f4* MEM4 = (f4*)MEM;
  int xcd = bid & 7, t2 = bid >> 3;
  int b = xcd*4 + (t2 & 3), ch8 = t2 >> 2;
  int hkh = tid >> 8, tl = tid & 255;       // half index, local tid
  if (tid < 512){
    int kk = tid >> 6, e = tid & 63;
    int n = kk & 3;
    int c = (kk >= 4) ? (64 + e) : e;
    keys[kk][e] = HPT[(n*129 + c)*32 + b];
  }
  if (t > 0){
    if (tid < 64){
      int n = tid >> 4, e4 = tid & 15;
      wkp[n][e4] = ((const f4*)WKS)[(b*4 + n)*16 + e4];
    }
    if (tid < 4){ gmp[tid] = WST[b*8 + tid*2]; facp[tid] = WST[b*8 + tid*2 + 1]; }
  }
  for (int sub = 0; sub < 2; ++sub){
    int ch = ch8*4 + hkh*2 + sub;
    __syncthreads();
    for (int idx = tl; idx < 64*16; idx += 256){
      int m = idx >> 4, e4 = idx & 15;
      ((f4*)&mc[hkh][m][0])[e4] = MEM4[((size_t)b*MS + ch*64 + m)*16 + e4];
    }
    if (t > 0){
      // ew from step t-1's scores (SW not yet overwritten for this chunk)
      int n = tl >> 6, m = tl & 63;
      float s = SW[((size_t)b*4 + n)*MS + ch*64 + m];
      ew[hkh][n][m] = __expf(s - gmp[n]) * facp[n];
    }
    __syncthreads();
    if (t > 0){
      for (int idx = tl; idx < 1024; idx += 256){
        int m = idx >> 4, e4 = idx & 15;
        f4 v = ((f4*)&mc[hkh][m][0])[e4];
        v += ew[hkh][0][m]*wkp[0][e4] + ew[hkh][1][m]*wkp[1][e4]
           + ew[hkh][2][m]*wkp[2][e4] + ew[hkh][3][m]*wkp[3][e4];
        ((f4*)&mc[hkh][m][0])[e4] = v;
        MEM4[((size_t)b*MS + ch*64 + m)*16 + e4] = v;
      }
      __syncthreads();
    }
    {
      int m = tl & 63, kp = tl >> 6;    // wave kp (within half) holds rows 2kp,2kp+1
      const f4* mrow4 = (const f4*)&mc[hkh][m][0];
      int k0 = kp*2, k1 = kp*2+1;
      f4 s0v = {0.f,0.f,0.f,0.f}, s1v = {0.f,0.f,0.f,0.f};
      #pragma unroll 4
      for (int e4 = 0; e4 < 16; ++e4){
        f4 mv = mrow4[e4];
        s0v += mv * (*(const f4*)&keys[k0][e4*4]);
        s1v += mv * (*(const f4*)&keys[k1][e4*4]);
      }
      float s0 = hsum(s0v)*0.125f, s1 = hsum(s1v)*0.125f;
      if (kp >= 2){
        float* swp = SW + ((size_t)b*4 + (k0-4))*MS + ch*64 + m;
        swp[0] = s0; swp[MS] = s1;
      }
      // in-wave softmax: max (exact) then exp then sum, rows span the 64 lanes
      float mx0 = s0, mx1 = s1;
      #pragma unroll
      for (int off = 32; off > 0; off >>= 1){
        mx0 = fmaxf(mx0, __shfl_xor(mx0, off, 64));
        mx1 = fmaxf(mx1, __shfl_xor(mx1, off, 64));
      }
      float e0 = __expf(s0 - mx0), e1 = __expf(s1 - mx1);
      float sm0 = e0, sm1 = e1;
      #pragma unroll
      for (int off = 32; off > 0; off >>= 1){
        sm0 += __shfl_xor(sm0, off, 64);
        sm1 += __shfl_xor(sm1, off, 64);
      }
      if (kp < 2){ sc[hkh][k0][m] = e0; sc[hkh][k1][m] = e1; }
      if (m == 0){
        float* pp = PART + (((size_t)b*NCH + ch)*8 + k0)*2;
        pp[0] = mx0; pp[1] = sm0;
        pp[2] = mx1; pp[3] = sm1;
      }
    }
    __syncthreads();
    {
      int n = tl >> 6, e = tl & 63;
      float pr = 0.f;
      for (int m = 0; m < 64; ++m) pr += sc[hkh][n][m] * mc[hkh][m][e];
      PREAD[(((size_t)b*NCH + ch)*4 + n)*64 + e] = pr;
    }
  }

  // ---- last-arriver tail (old k_Dlite) for batch b: 8 blocks -> last runs it ----
  __syncthreads();
  if (tid == 0){
    __builtin_amdgcn_fence(__ATOMIC_RELEASE, "agent");
    unsigned old = __hip_atomic_fetch_add(&DCNT[b], 1u, __ATOMIC_RELAXED,
                                          __HIP_MEMORY_SCOPE_AGENT);
    lastf = (old == 7u);
    if (old == 7u) __builtin_amdgcn_fence(__ATOMIC_ACQUIRE, "agent");
  }
  __syncthreads();
  if (!lastf) return;

  // last block of batch b: 512 threads alive, Dlite arithmetic uses first 256
  if (tid < 4){
    // write-side stats -> WST for next step's deferred update
    int kk = 4 + tid;
    const float* pp = PART + ((size_t)b*NCH*8 + kk)*2;
    float mx = -1e30f;
    for (int c2 = 0; c2 < NCH; ++c2) mx = fmaxf(mx, pp[c2*16]);
    float d = 0.f;
    for (int c2 = 0; c2 < NCH; ++c2) d += pp[c2*16+1]*__expf(pp[c2*16] - mx);
    float st = sigm(HPT[(tid*129 + 128)*32 + b]);
    WST[b*8 + tid*2]     = mx;
    WST[b*8 + tid*2 + 1] = st / d;
  }
  if (tid < 256){
    // save raw write keys (HPT will be overwritten next step)
    int n = tid >> 6, e = tid & 63;
    WKS[(b*4 + n)*64 + e] = HPT[(n*129 + 64 + e)*32 + b];
  }
  if (tid < 4){
    const float* pp = PART + ((size_t)b*NCH*8 + tid)*2;
    float mx = -1e30f;
    for (int c2 = 0; c2 < NCH; ++c2) mx = fmaxf(mx, pp[c2*16]);
    float d = 0.f;
    for (int c2 = 0; c2 < NCH; ++c2) d += pp[c2*16+1]*__expf(pp[c2*16] - mx);
    gm2[tid] = mx; dn2[tid] = d;
  }
  __syncthreads();
  if (tid < 256){
    int n = tid >> 6, e = tid & 63;
    float gmn = gm2[n], dnn = dn2[n];
    float r = 0.f;
    for (int c2 = 0; c2 < NCH; ++c2){
      float cm = PART[(((size_t)b*NCH + c2)*8 + n)*2];
      r += PREAD[(((size_t)b*NCH + c2)*4 + n)*64 + e] * __expf(cm - gmn);
    }
    r /= dnn;
    int k = n*64 + e;
    READT[(k>>2)*128 + b*4 + (k&3)] = r;
    RHIST[((size_t)t*64 + (k>>2))*128 + b*4 + (k&3)] = r;
  }
  if (t == T-1 && tid < 256){
    int i = b*256 + tid;       // 8192 slots, need 4096 f4
    if (i < 4096){
      int j4 = i & 127, bb = i >> 7;
      ((f4*)HF)[i] = ((const f4*)HHT)[((size_t)(T-1)*128 + j4)*32 + bb];
    }
  }
  if (tid == 0)
    __hip_atomic_store(&DCNT[b], 0u, __ATOMIC_RELAXED, __HIP_MEMORY_SCOPE_AGENT);
}

// ---------------- final mem-update flush for t = T-1 (256 blocks) ----------------
__global__ __launch_bounds__(256) void k_flush(
    float* __restrict__ MEM, const float* __restrict__ SW,
    const float* __restrict__ WST, const float* __restrict__ WKS)
{
  __shared__ float gm[4], fac[4];
  __shared__ f4 wk4[4][16];
  __shared__ float ew[4][256];
  const int bid = blockIdx.x, tid = threadIdx.x;
  int xcd = bid & 7, t2 = bid >> 3;
  int b = xcd*4 + (t2 & 3), sub = t2 >> 2;     // 8 chunks of 256 rows
  if (tid < 4){ gm[tid] = WST[b*8 + tid*2]; fac[tid] = WST[b*8 + tid*2 + 1]; }
  if (tid < 64){
    int n = tid >> 4, e4 = tid & 15;
    wk4[n][e4] = ((const f4*)WKS)[(b*4 + n)*16 + e4];
  }
  __syncthreads();
  for (int idx = tid; idx < 1024; idx += 256){
    int n = idx >> 8, m = idx & 255;
    float s = SW[((size_t)b*4 + n)*MS + sub*256 + m];
    ew[n][m] = __expf(s - gm[n]) * fac[n];
  }
  __syncthreads();
  {
    int e4 = tid & 15, ms = tid >> 4;
    f4 k0 = wk4[0][e4], k1 = wk4[1][e4], k2 = wk4[2][e4], k3 = wk4[3][e4];
    #pragma unroll 2
    for (int it = 0; it < 16; ++it){
      int m = it*16 + ms;
      float w0 = ew[0][m], w1 = ew[1][m];
      float w2 = ew[2][m], w3 = ew[3][m];
      f4* p = (f4*)MEM + ((size_t)b*MS + sub*256 + m)*16 + e4;
      f4 v = *p;
      v += w0*k0 + w1*k1 + w2*k2 + w3*k3;
      *p = v;
    }
  }
}

// ---------------- final output GEMM (256 blocks) ----------------
__global__ __launch_bounds__(256) void k_out(
    const float* __restrict__ HHT, const float* __restrict__ RHIST,
    const float* __restrict__ WT_OUT, const float* __restrict__ b_out,
    float* __restrict__ out)
{
  __shared__ float A[16][260];
  const int bid = blockIdx.x, tid = threadIdx.x;
  const f4* HHT4 = (const f4*)HHT;
  const f4* RHIST4 = (const f4*)RHIST;
  const f4* W4 = (const f4*)WT_OUT;
  int nt = bid & 3, mt = bid >> 2;
  int rl = tid & 15, og = tid >> 4;
  int o = nt*64 + og*4, o4 = o >> 2;
  f4 a0 = {0.f,0.f,0.f,0.f}, a1 = a0, a2 = a0, a3 = a0;
  for (int kc = 0; kc < 3; ++kc){
    __syncthreads();
    for (int idx = tid; idx < 1024; idx += 256){
      int r = idx >> 6, k4 = idx & 63;
      int row = mt*16 + r;
      int bb = row >> 5, tt = row & 31;
      int kg4 = kc*64 + k4;
      f4 v = (kg4 < 128)
        ? HHT4[((size_t)tt*128 + kg4)*32 + bb]
        : RHIST4[((size_t)tt*64 + (kg4-128))*32 + bb];
      *(f4*)&A[r][k4*4] = v;
    }
    __syncthreads();
    const float* Ar = &A[rl][0];
    const f4* wp = W4 + (size_t)kc*256*64 + o4;
    #pragma unroll 2
    for (int k = 0; k < 256; k += 4){
      a0 += Ar[k]   * wp[(size_t)(k)*64];
      a1 += Ar[k+1] * wp[(size_t)(k+1)*64];
      a2 += Ar[k+2] * wp[(size_t)(k+2)*64];
      a3 += Ar[k+3] * wp[(size_t)(k+3)*64];
    }
  }
  int row = mt*16 + rl;
  f4 accv = (a0 + a1) + (a2 + a3);
  accv += *(const f4*)(b_out + o);
  *(f4*)(out + (size_t)row*O_DIM + o) = accv;
}

extern "C" void kernel_launch(void* const* d_in, const int* in_sizes, int n_in,
                              void* d_out, int out_size, void* d_ws, size_t ws_size,
                              hipStream_t stream)
{
  const float* x      = (const float*)d_in[0];
  const float* W_ih   = (const float*)d_in[1];
  const float* W_hh   = (const float*)d_in[2];
  const float* b_ih   = (const float*)d_in[3];
  const float* b_hh   = (const float*)d_in[4];
  const float* W_head = (const float*)d_in[5];
  const float* b_head = (const float*)d_in[6];
  const float* W_out  = (const float*)d_in[7];
  const float* b_out  = (const float*)d_in[8];

  float* out = (float*)d_out;
  float* MEM = out + B*T*O_DIM;
  float* HF  = MEM + (size_t)B*MS*HS;
  float* CF  = HF + B*H_DIM;

  float* ws      = (float*)d_ws;
  float* WT_HD2  = ws;                          // 520*512   = 266240
  float* WT_OUT  = WT_HD2 + 520*512;            // 768*256   = 196608
  float* XT      = WT_OUT + 768*256;            // 262144
  float* SW      = XT     + 262144;             // 32*4*2048 = 262144
  float* PART    = SW     + 262144;             // 32*32*8*2 = 16384
  float* PREAD   = PART   + 16384;              // 32*32*4*64= 262144
  float* HPT     = PREAD  + 262144;             // 520*32    = 16640
  float* READT   = HPT    + 16640;              // 256*32    = 8192
  unsigned* DCNT = (unsigned*)(READT + 8192);   // 32 counters (zeroed w/ READT)
  float* HHT     = READT  + 8192 + 32;          // 32*512*32 = 524288
  float* RHIST   = HHT    + 524288;             // 32*256*32 = 262144
  float* WST     = RHIST  + 262144;             // 32*8      = 256
  float* WKS     = WST    + 256;                // 32*4*64   = 8192

  (void)hipMemsetAsync(MEM, 0, ((size_t)B*MS*HS + 2*B*H_DIM)*sizeof(float), stream);
  (void)hipMemsetAsync(READT, 0, (size_t)(8192 + 32)*sizeof(float), stream);

  k_ghead<<<1040, 256, 0, stream>>>(WT_HD2, W_head);
  k_transpose_t<<<dim3(8, 24), 256, 0, stream>>>(WT_OUT, W_out, 256, 768);
  k_xt<<<256, 256, 0, stream>>>((f4*)XT, x);

  for (int t = 0; t < T; ++t){
    k_A<<<256, 512, 0, stream>>>((const f4*)XT, W_ih, W_hh, b_ih, b_hh,
                                 (const f4*)READT, HHT, CF, t);
    k_B<<<260, 256, 0, stream>>>(HHT, WT_HD2, b_head, HPT, t);
    k_CDD<<<256, 512, 0, stream>>>(MEM, HPT, SW, PART, PREAD, WST, WKS,
                                   READT, RHIST, HHT, HF, DCNT, t);
  }
  k_flush<<<256, 256, 0, stream>>>(MEM, SW, WST, WKS);
  k_out<<<256, 256, 0, stream>>>(HHT, RHIST, WT_OUT, b_out, out);
}

// Round 9
// 1235.213 us; speedup vs baseline: 1.0452x; 1.0452x over previous
//
#include <hip/hip_runtime.h>
#include <math.h>

#define B 32
#define T 32
#define O_DIM 256
#define H_DIM 512
#define HS 64
#define MS 2048
#define NCOL 516
#define NCH 32          // 64-row softmax chunks

typedef __attribute__((ext_vector_type(4))) float f4;

__device__ __forceinline__ float sigm(float x){ return 1.0f/(1.0f+__expf(-x)); }
__device__ __forceinline__ float hsum(f4 v){ return (v.x + v.y) + (v.z + v.w); }

// ---------------- prep kernels ----------------
__global__ __launch_bounds__(256) void k_transpose_t(float* __restrict__ dst,
                                                     const float* __restrict__ src,
                                                     int N, int K){
  __shared__ float tile[32][33];
  int jb = blockIdx.x*32, kb = blockIdx.y*32;
  int tj = threadIdx.x & 31, tk = threadIdx.x >> 5;
  #pragma unroll
  for (int p = 0; p < 4; ++p){
    int j = jb + tk + p*8, k = kb + tj;
    if (j < N && k < K) tile[tk + p*8][tj] = src[j*K + k];
  }
  __syncthreads();
  #pragma unroll
  for (int p = 0; p < 4; ++p){
    int k = kb + tk + p*8, j = jb + tj;
    if (j < N && k < K) dst[k*N + j] = tile[tj][tk + p*8];
  }
}

__global__ __launch_bounds__(256) void k_ghead(float* __restrict__ dst,
                                               const float* __restrict__ W_head){
  int idx = blockIdx.x*256 + threadIdx.x;     // col*512 + k
  if (idx >= 520*512) return;
  int col = idx >> 9, k = idx & 511;
  float v = 0.f;
  if (col < NCOL){ int n = col/129, c = col%129; v = W_head[((size_t)n*2115 + c)*512 + k]; }
  dst[idx] = v;
}

__global__ __launch_bounds__(256) void k_xt(f4* __restrict__ XT4,
                                            const float* __restrict__ x){
  int idx = blockIdx.x*256 + threadIdx.x;     // t*2048 + k4*32 + b
  int b = idx & 31, k4 = (idx >> 5) & 63, t = idx >> 11;
  XT4[idx] = ((const f4*)x)[(size_t)(b*T + t)*64 + k4];
}

// ---------------- PH_A: gates GEMM + LSTM (256 blocks x 512 thr) ----------------
// k-split: waves 0-3 (khalf=0) do x+read half; waves 4-7 (khalf=1) do h half.
__global__ __launch_bounds__(512) void k_A(
    const f4* __restrict__ XT4, const float* __restrict__ W_ih,
    const float* __restrict__ W_hh, const float* __restrict__ b_ih,
    const float* __restrict__ b_hh, const f4* __restrict__ READT4,
    float* __restrict__ HHT, float* __restrict__ CF, int t)
{
  __shared__ f4 WS[8*256];         // 8 rows x (128 f4 W_ih + 128 f4 W_hh) = 32 KB
  __shared__ float glp[2][8][33];  // per-khalf partials
  const int bid = blockIdx.x, tid = threadIdx.x;
  const f4* HHT4 = (const f4*)HHT;
  for (int idx = tid; idx < 2048; idx += 512){
    int rsub = idx >> 8, q = idx & 255;
    int gate = rsub & 3, jj = (rsub >> 2) & 1;
    int row = gate*512 + bid*2 + jj;
    WS[idx] = (q < 128) ? ((const f4*)W_ih)[(size_t)row*128 + q]
                        : ((const f4*)W_hh)[(size_t)row*128 + (q - 128)];
  }
  __syncthreads();
  {
    int b = tid & 31, rsub = (tid >> 5) & 7, khalf = tid >> 8;
    const f4* w = WS + rsub*256;
    f4 a0 = {0.f,0.f,0.f,0.f}, a1 = {0.f,0.f,0.f,0.f};
    if (khalf == 0){
      const f4* xt4 = XT4 + (size_t)t*2048;
      #pragma unroll 4
      for (int k4 = 0; k4 < 64; k4 += 2){
        a0 += w[k4]     * xt4[k4*32 + b];
        a1 += w[k4+1]   * xt4[(k4+1)*32 + b];
      }
      #pragma unroll 4
      for (int k4 = 0; k4 < 64; k4 += 2){
        a0 += w[64+k4]   * READT4[k4*32 + b];
        a1 += w[64+k4+1] * READT4[(k4+1)*32 + b];
      }
    } else if (t > 0){
      const f4* ht4 = HHT4 + (size_t)(t-1)*4096;
      #pragma unroll 4
      for (int k4 = 0; k4 < 128; k4 += 2){
        a0 += w[128+k4]   * ht4[k4*32 + b];
        a1 += w[128+k4+1] * ht4[(k4+1)*32 + b];
      }
    }
    glp[khalf][rsub][b] = hsum(a0 + a1);
  }
  __syncthreads();
  if (tid < 64){
    int b2 = tid & 31, jj2 = tid >> 5;
    int j2 = bid*2 + jj2;
    int r0 = 0*512 + j2, r1 = 1*512 + j2, r2 = 2*512 + j2, r3 = 3*512 + j2;
    float gi = glp[0][jj2*4+0][b2] + glp[1][jj2*4+0][b2] + b_ih[r0] + b_hh[r0];
    float gf = glp[0][jj2*4+1][b2] + glp[1][jj2*4+1][b2] + b_ih[r1] + b_hh[r1];
    float gg = glp[0][jj2*4+2][b2] + glp[1][jj2*4+2][b2] + b_ih[r2] + b_hh[r2];
    float go = glp[0][jj2*4+3][b2] + glp[1][jj2*4+3][b2] + b_ih[r3] + b_hh[r3];
    float c = sigm(gf)*CF[b2*512+j2] + sigm(gi)*tanhf(gg);
    float h = sigm(go)*tanhf(c);
    CF[b2*512+j2] = c;
    HHT[((size_t)t*128 + (j2>>2))*128 + b2*4 + (j2&3)] = h;
  }
}

// ---------------- PH_B: head projection (260 blocks, 2 cols, 4-way k-split) ----
__global__ __launch_bounds__(256) void k_B(
    const float* __restrict__ HHT, const float* __restrict__ WT_HD2,
    const float* __restrict__ b_head, float* __restrict__ HPT, int t)
{
  __shared__ float red[256];
  const int bid = blockIdx.x, tid = threadIdx.x;
  const f4* HHT4 = (const f4*)HHT;
  int b = tid & 31, cs = (tid>>5)&1, kq = tid>>6;   // kq in 0..3
  int col = bid*2 + cs;
  const f4* hT4 = HHT4 + (size_t)t*4096 + kq*1024;  // quarter of k (32 f4)
  const f4* w4  = (const f4*)(WT_HD2 + (size_t)col*512) + kq*32;
  f4 acc4 = {0.f, 0.f, 0.f, 0.f};
  #pragma unroll 4
  for (int k4 = 0; k4 < 32; ++k4)
    acc4 += w4[k4] * hT4[k4*32 + b];
  red[tid] = hsum(acc4);
  __syncthreads();
  if (kq == 0){
    float v = red[tid] + red[tid + 64] + red[tid + 128] + red[tid + 192];
    if (col < NCOL){ int n = col/129, c = col%129; v += b_head[n*2115 + c]; }
    HPT[col*32 + b] = v;
  }
}

// ---- PH_CD: deferred mem-update + scores + wave-softmax + partial reads ----
// 512 blocks x 256 thr: block handles 2 chunks (ch16*2 + sub). Same per-chunk
// arithmetic as R7; halves now in independent blocks (decoupled barriers).
__global__ __launch_bounds__(256) void k_CD(
    float* __restrict__ MEM, const float* __restrict__ HPT,
    float* __restrict__ SW, float* __restrict__ PART, float* __restrict__ PREAD,
    const float* __restrict__ WST, const float* __restrict__ WKS, int t)
{
  __shared__ float keys[8][64];
  __shared__ float mc[64][68];
  __shared__ float sc[4][64];
  __shared__ float ew[4][64];
  __shared__ f4 wkp[4][16];
  __shared__ float gmp[4], facp[4];
  const int bid = blockIdx.x, tid = threadIdx.x;
  f4* MEM4 = (f4*)MEM;
  int xcd = bid & 7, r = bid >> 3;
  int b = xcd*4 + (r & 3), ch16 = r >> 2;     // 16 blocks per batch
  for (int idx = tid; idx < 512; idx += 256){
    int kk = idx >> 6, e = idx & 63;
    int n = kk & 3;
    int c = (kk >= 4) ? (64 + e) : e;
    keys[kk][e] = HPT[(n*129 + c)*32 + b];
  }
  if (t > 0){
    if (tid < 64){
      int n = tid >> 4, e4 = tid & 15;
      wkp[n][e4] = ((const f4*)WKS)[(b*4 + n)*16 + e4];
    }
    if (tid < 4){ gmp[tid] = WST[b*8 + tid*2]; facp[tid] = WST[b*8 + tid*2 + 1]; }
  }
  for (int sub = 0; sub < 2; ++sub){
    int ch = ch16*2 + sub;
    __syncthreads();
    for (int idx = tid; idx < 64*16; idx += 256){
      int m = idx >> 4, e4 = idx & 15;
      ((f4*)&mc[m][0])[e4] = MEM4[((size_t)b*MS + ch*64 + m)*16 + e4];
    }
    if (t > 0){
      // ew from step t-1's scores (SW not yet overwritten for this chunk)
      int n = tid >> 6, m = tid & 63;
      float s = SW[((size_t)b*4 + n)*MS + ch*64 + m];
      ew[n][m] = __expf(s - gmp[n]) * facp[n];
    }
    __syncthreads();
    if (t > 0){
      for (int idx = tid; idx < 1024; idx += 256){
        int m = idx >> 4, e4 = idx & 15;
        f4 v = ((f4*)&mc[m][0])[e4];
        v += ew[0][m]*wkp[0][e4] + ew[1][m]*wkp[1][e4]
           + ew[2][m]*wkp[2][e4] + ew[3][m]*wkp[3][e4];
        ((f4*)&mc[m][0])[e4] = v;
        MEM4[((size_t)b*MS + ch*64 + m)*16 + e4] = v;
      }
      __syncthreads();
    }
    {
      int m = tid & 63, kp = tid >> 6;    // wave kp holds rows 2kp, 2kp+1
      const f4* mrow4 = (const f4*)&mc[m][0];
      int k0 = kp*2, k1 = kp*2+1;
      f4 s0v = {0.f,0.f,0.f,0.f}, s1v = {0.f,0.f,0.f,0.f};
      #pragma unroll 4
      for (int e4 = 0; e4 < 16; ++e4){
        f4 mv = mrow4[e4];
        s0v += mv * (*(const f4*)&keys[k0][e4*4]);
        s1v += mv * (*(const f4*)&keys[k1][e4*4]);
      }
      float s0 = hsum(s0v)*0.125f, s1 = hsum(s1v)*0.125f;
      if (kp >= 2){
        float* swp = SW + ((size_t)b*4 + (k0-4))*MS + ch*64 + m;
        swp[0] = s0; swp[MS] = s1;
      }
      // in-wave softmax: max (exact) then exp then sum, rows span the 64 lanes
      float mx0 = s0, mx1 = s1;
      #pragma unroll
      for (int off = 32; off > 0; off >>= 1){
        mx0 = fmaxf(mx0, __shfl_xor(mx0, off, 64));
        mx1 = fmaxf(mx1, __shfl_xor(mx1, off, 64));
      }
      float e0 = __expf(s0 - mx0), e1 = __expf(s1 - mx1);
      float sm0 = e0, sm1 = e1;
      #pragma unroll
      for (int off = 32; off > 0; off >>= 1){
        sm0 += __shfl_xor(sm0, off, 64);
        sm1 += __shfl_xor(sm1, off, 64);
      }
      if (kp < 2){ sc[k0][m] = e0; sc[k1][m] = e1; }
      if (m == 0){
        float* pp = PART + (((size_t)b*NCH + ch)*8 + k0)*2;
        pp[0] = mx0; pp[1] = sm0;
        pp[2] = mx1; pp[3] = sm1;
      }
    }
    __syncthreads();
    {
      int n = tid >> 6, e = tid & 63;
      float pr = 0.f;
      for (int m = 0; m < 64; ++m) pr += sc[n][m] * mc[m][e];
      PREAD[(((size_t)b*NCH + ch)*4 + n)*64 + e] = pr;
    }
  }
}

// ---- PH_Dlite: read merge + write-side stats + wk save (+HF copy) (32 blocks) ----
__global__ __launch_bounds__(256) void k_Dlite(
    const float* __restrict__ HPT, const float* __restrict__ PART,
    const float* __restrict__ PREAD, float* __restrict__ READT,
    float* __restrict__ RHIST, float* __restrict__ WST, float* __restrict__ WKS,
    const float* __restrict__ HHT, float* __restrict__ HF, int t)
{
  __shared__ float gm2[4], dn2[4];
  const int bid = blockIdx.x, tid = threadIdx.x;
  const f4* HHT4 = (const f4*)HHT;
  int b = bid;
  if (tid < 4){
    // write-side stats -> WST for next step's deferred update
    int kk = 4 + tid;
    const float* pp = PART + ((size_t)b*NCH*8 + kk)*2;
    float mx = -1e30f;
    for (int ch = 0; ch < NCH; ++ch) mx = fmaxf(mx, pp[ch*16]);
    float d = 0.f;
    for (int ch = 0; ch < NCH; ++ch) d += pp[ch*16+1]*__expf(pp[ch*16] - mx);
    float st = sigm(HPT[(tid*129 + 128)*32 + b]);
    WST[b*8 + tid*2]     = mx;
    WST[b*8 + tid*2 + 1] = st / d;
  }
  {
    // save raw write keys (HPT will be overwritten next step)
    int n = tid >> 6, e = tid & 63;
    WKS[(b*4 + n)*64 + e] = HPT[(n*129 + 64 + e)*32 + b];
  }
  if (tid < 4){
    const float* pp = PART + ((size_t)b*NCH*8 + tid)*2;
    float mx = -1e30f;
    for (int ch = 0; ch < NCH; ++ch) mx = fmaxf(mx, pp[ch*16]);
    float d = 0.f;
    for (int ch = 0; ch < NCH; ++ch) d += pp[ch*16+1]*__expf(pp[ch*16] - mx);
    gm2[tid] = mx; dn2[tid] = d;
  }
  __syncthreads();
  {
    int n = tid >> 6, e = tid & 63;
    float gmn = gm2[n], dnn = dn2[n];
    float r = 0.f;
    for (int ch = 0; ch < NCH; ++ch){
      float cm = PART[(((size_t)b*NCH + ch)*8 + n)*2];
      r += PREAD[(((size_t)b*NCH + ch)*4 + n)*64 + e] * __expf(cm - gmn);
    }
    r /= dnn;
    int k = n*64 + e;
    READT[(k>>2)*128 + b*4 + (k&3)] = r;
    RHIST[((size_t)t*64 + (k>>2))*128 + b*4 + (k&3)] = r;
  }
  if (t == T-1){
    int i = bid*256 + tid;       // 8192 slots, need 4096 f4
    if (i < 4096){
      int j4 = i & 127, bb = i >> 7;
      ((f4*)HF)[i] = HHT4[((size_t)(T-1)*128 + j4)*32 + bb];
    }
  }
}

// ---------------- final mem-update flush for t = T-1 (256 blocks) ----------------
__global__ __launch_bounds__(256) void k_flush(
    float* __restrict__ MEM, const float* __restrict__ SW,
    const float* __restrict__ WST, const float* __restrict__ WKS)
{
  __shared__ float gm[4], fac[4];
  __shared__ f4 wk4[4][16];
  __shared__ float ew[4][256];
  const int bid = blockIdx.x, tid = threadIdx.x;
  int xcd = bid & 7, t2 = bid >> 3;
  int b = xcd*4 + (t2 & 3), sub = t2 >> 2;     // 8 chunks of 256 rows
  if (tid < 4){ gm[tid] = WST[b*8 + tid*2]; fac[tid] = WST[b*8 + tid*2 + 1]; }
  if (tid < 64){
    int n = tid >> 4, e4 = tid & 15;
    wk4[n][e4] = ((const f4*)WKS)[(b*4 + n)*16 + e4];
  }
  __syncthreads();
  for (int idx = tid; idx < 1024; idx += 256){
    int n = idx >> 8, m = idx & 255;
    float s = SW[((size_t)b*4 + n)*MS + sub*256 + m];
    ew[n][m] = __expf(s - gm[n]) * fac[n];
  }
  __syncthreads();
  {
    int e4 = tid & 15, ms = tid >> 4;
    f4 k0 = wk4[0][e4], k1 = wk4[1][e4], k2 = wk4[2][e4], k3 = wk4[3][e4];
    #pragma unroll 2
    for (int it = 0; it < 16; ++it){
      int m = it*16 + ms;
      float w0 = ew[0][m], w1 = ew[1][m];
      float w2 = ew[2][m], w3 = ew[3][m];
      f4* p = (f4*)MEM + ((size_t)b*MS + sub*256 + m)*16 + e4;
      f4 v = *p;
      v += w0*k0 + w1*k1 + w2*k2 + w3*k3;
      *p = v;
    }
  }
}

// ---------------- final output GEMM (256 blocks) ----------------
__global__ __launch_bounds__(256) void k_out(
    const float* __restrict__ HHT, const float* __restrict__ RHIST,
    const float* __restrict__ WT_OUT, const float* __restrict__ b_out,
    float* __restrict__ out)
{
  __shared__ float A[16][260];
  const int bid = blockIdx.x, tid = threadIdx.x;
  const f4* HHT4 = (const f4*)HHT;
  const f4* RHIST4 = (const f4*)RHIST;
  const f4* W4 = (const f4*)WT_OUT;
  int nt = bid & 3, mt = bid >> 2;
  int rl = tid & 15, og = tid >> 4;
  int o = nt*64 + og*4, o4 = o >> 2;
  f4 a0 = {0.f,0.f,0.f,0.f}, a1 = a0, a2 = a0, a3 = a0;
  for (int kc = 0; kc < 3; ++kc){
    __syncthreads();
    for (int idx = tid; idx < 1024; idx += 256){
      int r = idx >> 6, k4 = idx & 63;
      int row = mt*16 + r;
      int bb = row >> 5, tt = row & 31;
      int kg4 = kc*64 + k4;
      f4 v = (kg4 < 128)
        ? HHT4[((size_t)tt*128 + kg4)*32 + bb]
        : RHIST4[((size_t)tt*64 + (kg4-128))*32 + bb];
      *(f4*)&A[r][k4*4] = v;
    }
    __syncthreads();
    const float* Ar = &A[rl][0];
    const f4* wp = W4 + (size_t)kc*256*64 + o4;
    #pragma unroll 2
    for (int k = 0; k < 256; k += 4){
      a0 += Ar[k]   * wp[(size_t)(k)*64];
      a1 += Ar[k+1] * wp[(size_t)(k+1)*64];
      a2 += Ar[k+2] * wp[(size_t)(k+2)*64];
      a3 += Ar[k+3] * wp[(size_t)(k+3)*64];
    }
  }
  int row = mt*16 + rl;
  f4 accv = (a0 + a1) + (a2 + a3);
  accv += *(const f4*)(b_out + o);
  *(f4*)(out + (size_t)row*O_DIM + o) = accv;
}

extern "C" void kernel_launch(void* const* d_in, const int* in_sizes, int n_in,
                              void* d_out, int out_size, void* d_ws, size_t ws_size,
                              hipStream_t stream)
{
  const float* x      = (const float*)d_in[0];
  const float* W_ih   = (const float*)d_in[1];
  const float* W_hh   = (const float*)d_in[2];
  const float* b_ih   = (const float*)d_in[3];
  const float* b_hh   = (const float*)d_in[4];
  const float* W_head = (const float*)d_in[5];
  const float* b_head = (const float*)d_in[6];
  const float* W_out  = (const float*)d_in[7];
  const float* b_out  = (const float*)d_in[8];

  float* out = (float*)d_out;
  float* MEM = out + B*T*O_DIM;
  float* HF  = MEM + (size_t)B*MS*HS;
  float* CF  = HF + B*H_DIM;

  float* ws      = (float*)d_ws;
  float* WT_HD2  = ws;                          // 520*512   = 266240
  float* WT_OUT  = WT_HD2 + 520*512;            // 768*256   = 196608
  float* XT      = WT_OUT + 768*256;            // 262144
  float* SW      = XT     + 262144;             // 32*4*2048 = 262144
  float* PART    = SW     + 262144;             // 32*32*8*2 = 16384
  float* PREAD   = PART   + 16384;              // 32*32*4*64= 262144
  float* HPT     = PREAD  + 262144;             // 520*32    = 16640
  float* READT   = HPT    + 16640;              // 256*32    = 8192
  float* HHT     = READT  + 8192;               // 32*512*32 = 524288
  float* RHIST   = HHT    + 524288;             // 32*256*32 = 262144
  float* WST     = RHIST  + 262144;             // 32*8      = 256
  float* WKS     = WST    + 256;                // 32*4*64   = 8192

  (void)hipMemsetAsync(MEM, 0, ((size_t)B*MS*HS + 2*B*H_DIM)*sizeof(float), stream);
  (void)hipMemsetAsync(READT, 0, (size_t)8192*sizeof(float), stream);

  k_ghead<<<1040, 256, 0, stream>>>(WT_HD2, W_head);
  k_transpose_t<<<dim3(8, 24), 256, 0, stream>>>(WT_OUT, W_out, 256, 768);
  k_xt<<<256, 256, 0, stream>>>((f4*)XT, x);

  for (int t = 0; t < T; ++t){
    k_A<<<256, 512, 0, stream>>>((const f4*)XT, W_ih, W_hh, b_ih, b_hh,
                                 (const f4*)READT, HHT, CF, t);
    k_B<<<260, 256, 0, stream>>>(HHT, WT_HD2, b_head, HPT, t);
    k_CD<<<512, 256, 0, stream>>>(MEM, HPT, SW, PART, PREAD, WST, WKS, t);
    k_Dlite<<<32, 256, 0, stream>>>(HPT, PART, PREAD, READT, RHIST, WST, WKS,
                                    HHT, HF, t);
  }
  k_flush<<<256, 256, 0, stream>>>(MEM, SW, WST, WKS);
  k_out<<<256, 256, 0, stream>>>(HHT, RHIST, WT_OUT, b_out, out);
}

// Round 10
// 1184.986 us; speedup vs baseline: 1.0895x; 1.0424x over previous
//
#include <hip/hip_runtime.h>
#include <math.h>

#define B 32
#define T 32
#define O_DIM 256
#define H_DIM 512
#define HS 64
#define MS 2048
#define NCOL 516
#define NCH 32          // 64-row softmax chunks

typedef __attribute__((ext_vector_type(4))) float f4;

__device__ __forceinline__ float sigm(float x){ return 1.0f/(1.0f+__expf(-x)); }
__device__ __forceinline__ float hsum(f4 v){ return (v.x + v.y) + (v.z + v.w); }

// ---------------- prep kernels ----------------
__global__ __launch_bounds__(256) void k_transpose_t(float* __restrict__ dst,
                                                     const float* __restrict__ src,
                                                     int N, int K){
  __shared__ float tile[32][33];
  int jb = blockIdx.x*32, kb = blockIdx.y*32;
  int tj = threadIdx.x & 31, tk = threadIdx.x >> 5;
  #pragma unroll
  for (int p = 0; p < 4; ++p){
    int j = jb + tk + p*8, k = kb + tj;
    if (j < N && k < K) tile[tk + p*8][tj] = src[j*K + k];
  }
  __syncthreads();
  #pragma unroll
  for (int p = 0; p < 4; ++p){
    int k = kb + tk + p*8, j = jb + tj;
    if (j < N && k < K) dst[k*N + j] = tile[tj][tk + p*8];
  }
}

__global__ __launch_bounds__(256) void k_ghead(float* __restrict__ dst,
                                               const float* __restrict__ W_head){
  int idx = blockIdx.x*256 + threadIdx.x;     // col*512 + k
  if (idx >= 520*512) return;
  int col = idx >> 9, k = idx & 511;
  float v = 0.f;
  if (col < NCOL){ int n = col/129, c = col%129; v = W_head[((size_t)n*2115 + c)*512 + k]; }
  dst[idx] = v;
}

__global__ __launch_bounds__(256) void k_xt(f4* __restrict__ XT4,
                                            const float* __restrict__ x){
  int idx = blockIdx.x*256 + threadIdx.x;     // t*2048 + k4*32 + b
  int b = idx & 31, k4 = (idx >> 5) & 63, t = idx >> 11;
  XT4[idx] = ((const f4*)x)[(size_t)(b*T + t)*64 + k4];
}

// ---------------- PH_A: gates GEMM + LSTM (256 blocks x 512 thr) ----------------
// k-split: waves 0-3 (khalf=0) do x+read half; waves 4-7 (khalf=1) do h half.
__global__ __launch_bounds__(512) void k_A(
    const f4* __restrict__ XT4, const float* __restrict__ W_ih,
    const float* __restrict__ W_hh, const float* __restrict__ b_ih,
    const float* __restrict__ b_hh, const f4* __restrict__ READT4,
    float* __restrict__ HHT, float* __restrict__ CF, int t)
{
  __shared__ f4 WS[8*256];         // 8 rows x (128 f4 W_ih + 128 f4 W_hh) = 32 KB
  __shared__ float glp[2][8][33];  // per-khalf partials
  const int bid = blockIdx.x, tid = threadIdx.x;
  const f4* HHT4 = (const f4*)HHT;
  for (int idx = tid; idx < 2048; idx += 512){
    int rsub = idx >> 8, q = idx & 255;
    int gate = rsub & 3, jj = (rsub >> 2) & 1;
    int row = gate*512 + bid*2 + jj;
    WS[idx] = (q < 128) ? ((const f4*)W_ih)[(size_t)row*128 + q]
                        : ((const f4*)W_hh)[(size_t)row*128 + (q - 128)];
  }
  __syncthreads();
  {
    int b = tid & 31, rsub = (tid >> 5) & 7, khalf = tid >> 8;
    const f4* w = WS + rsub*256;
    f4 a0 = {0.f,0.f,0.f,0.f}, a1 = {0.f,0.f,0.f,0.f};
    if (khalf == 0){
      const f4* xt4 = XT4 + (size_t)t*2048;
      #pragma unroll 4
      for (int k4 = 0; k4 < 64; k4 += 2){
        a0 += w[k4]     * xt4[k4*32 + b];
        a1 += w[k4+1]   * xt4[(k4+1)*32 + b];
      }
      #pragma unroll 4
      for (int k4 = 0; k4 < 64; k4 += 2){
        a0 += w[64+k4]   * READT4[k4*32 + b];
        a1 += w[64+k4+1] * READT4[(k4+1)*32 + b];
      }
    } else if (t > 0){
      const f4* ht4 = HHT4 + (size_t)(t-1)*4096;
      #pragma unroll 4
      for (int k4 = 0; k4 < 128; k4 += 2){
        a0 += w[128+k4]   * ht4[k4*32 + b];
        a1 += w[128+k4+1] * ht4[(k4+1)*32 + b];
      }
    }
    glp[khalf][rsub][b] = hsum(a0 + a1);
  }
  __syncthreads();
  if (tid < 64){
    int b2 = tid & 31, jj2 = tid >> 5;
    int j2 = bid*2 + jj2;
    int r0 = 0*512 + j2, r1 = 1*512 + j2, r2 = 2*512 + j2, r3 = 3*512 + j2;
    float gi = glp[0][jj2*4+0][b2] + glp[1][jj2*4+0][b2] + b_ih[r0] + b_hh[r0];
    float gf = glp[0][jj2*4+1][b2] + glp[1][jj2*4+1][b2] + b_ih[r1] + b_hh[r1];
    float gg = glp[0][jj2*4+2][b2] + glp[1][jj2*4+2][b2] + b_ih[r2] + b_hh[r2];
    float go = glp[0][jj2*4+3][b2] + glp[1][jj2*4+3][b2] + b_ih[r3] + b_hh[r3];
    float c = sigm(gf)*CF[b2*512+j2] + sigm(gi)*tanhf(gg);
    float h = sigm(go)*tanhf(c);
    CF[b2*512+j2] = c;
    HHT[((size_t)t*128 + (j2>>2))*128 + b2*4 + (j2&3)] = h;
  }
}

// ---------------- PH_B: head projection (260 blocks, 2 cols, 4-way k-split) ----
__global__ __launch_bounds__(256) void k_B(
    const float* __restrict__ HHT, const float* __restrict__ WT_HD2,
    const float* __restrict__ b_head, float* __restrict__ HPT, int t)
{
  __shared__ float red[256];
  const int bid = blockIdx.x, tid = threadIdx.x;
  const f4* HHT4 = (const f4*)HHT;
  int b = tid & 31, cs = (tid>>5)&1, kq = tid>>6;   // kq in 0..3
  int col = bid*2 + cs;
  const f4* hT4 = HHT4 + (size_t)t*4096 + kq*1024;  // quarter of k (32 f4)
  const f4* w4  = (const f4*)(WT_HD2 + (size_t)col*512) + kq*32;
  f4 acc4 = {0.f, 0.f, 0.f, 0.f};
  #pragma unroll 4
  for (int k4 = 0; k4 < 32; ++k4)
    acc4 += w4[k4] * hT4[k4*32 + b];
  red[tid] = hsum(acc4);
  __syncthreads();
  if (kq == 0){
    float v = red[tid] + red[tid + 64] + red[tid + 128] + red[tid + 192];
    if (col < NCOL){ int n = col/129, c = col%129; v += b_head[n*2115 + c]; }
    HPT[col*32 + b] = v;
  }
}

// ---- PH_CD: deferred mem-update + scores + wave-softmax + partial reads ----
// 256 blocks x 512 thr: half hkh = tid>>8 handles chunks ch8*4 + hkh*2 + {0,1}.
// Softmax reductions done fully in-wave (each score row spans one wave's lanes).
__global__ __launch_bounds__(512) void k_CD(
    float* __restrict__ MEM, const float* __restrict__ HPT,
    float* __restrict__ SW, float* __restrict__ PART, float* __restrict__ PREAD,
    const float* __restrict__ WST, const float* __restrict__ WKS, int t)
{
  __shared__ float keys[8][64];
  __shared__ float mc[2][64][68];
  __shared__ float sc[2][4][64];
  __shared__ float ew[2][4][64];
  __shared__ f4 wkp[4][16];
  __shared__ float gmp[4], facp[4];
  const int bid = blockIdx.x, tid = threadIdx.x;
  f4* MEM4 = (f4*)MEM;
  int xcd = bid & 7, t2 = bid >> 3;
  int b = xcd*4 + (t2 & 3), ch8 = t2 >> 2;
  int hkh = tid >> 8, tl = tid & 255;       // half index, local tid
  if (tid < 512){
    int kk = tid >> 6, e = tid & 63;
    int n = kk & 3;
    int c = (kk >= 4) ? (64 + e) : e;
    keys[kk][e] = HPT[(n*129 + c)*32 + b];
  }
  if (t > 0){
    if (tid < 64){
      int n = tid >> 4, e4 = tid & 15;
      wkp[n][e4] = ((const f4*)WKS)[(b*4 + n)*16 + e4];
    }
    if (tid < 4){ gmp[tid] = WST[b*8 + tid*2]; facp[tid] = WST[b*8 + tid*2 + 1]; }
  }
  for (int sub = 0; sub < 2; ++sub){
    int ch = ch8*4 + hkh*2 + sub;
    __syncthreads();
    for (int idx = tl; idx < 64*16; idx += 256){
      int m = idx >> 4, e4 = idx & 15;
      ((f4*)&mc[hkh][m][0])[e4] = MEM4[((size_t)b*MS + ch*64 + m)*16 + e4];
    }
    if (t > 0){
      // ew from step t-1's scores (SW not yet overwritten for this chunk)
      int n = tl >> 6, m = tl & 63;
      float s = SW[((size_t)b*4 + n)*MS + ch*64 + m];
      ew[hkh][n][m] = __expf(s - gmp[n]) * facp[n];
    }
    __syncthreads();
    if (t > 0){
      for (int idx = tl; idx < 1024; idx += 256){
        int m = idx >> 4, e4 = idx & 15;
        f4 v = ((f4*)&mc[hkh][m][0])[e4];
        v += ew[hkh][0][m]*wkp[0][e4] + ew[hkh][1][m]*wkp[1][e4]
           + ew[hkh][2][m]*wkp[2][e4] + ew[hkh][3][m]*wkp[3][e4];
        ((f4*)&mc[hkh][m][0])[e4] = v;
        MEM4[((size_t)b*MS + ch*64 + m)*16 + e4] = v;
      }
      __syncthreads();
    }
    {
      int m = tl & 63, kp = tl >> 6;    // wave kp (within half) holds rows 2kp,2kp+1
      const f4* mrow4 = (const f4*)&mc[hkh][m][0];
      int k0 = kp*2, k1 = kp*2+1;
      f4 s0v = {0.f,0.f,0.f,0.f}, s1v = {0.f,0.f,0.f,0.f};
      #pragma unroll 4
      for (int e4 = 0; e4 < 16; ++e4){
        f4 mv = mrow4[e4];
        s0v += mv * (*(const f4*)&keys[k0][e4*4]);
        s1v += mv * (*(const f4*)&keys[k1][e4*4]);
      }
      float s0 = hsum(s0v)*0.125f, s1 = hsum(s1v)*0.125f;
      if (kp >= 2){
        float* swp = SW + ((size_t)b*4 + (k0-4))*MS + ch*64 + m;
        swp[0] = s0; swp[MS] = s1;
      }
      // in-wave softmax: max (exact) then exp then sum, rows span the 64 lanes
      float mx0 = s0, mx1 = s1;
      #pragma unroll
      for (int off = 32; off > 0; off >>= 1){
        mx0 = fmaxf(mx0, __shfl_xor(mx0, off, 64));
        mx1 = fmaxf(mx1, __shfl_xor(mx1, off, 64));
      }
      float e0 = __expf(s0 - mx0), e1 = __expf(s1 - mx1);
      float sm0 = e0, sm1 = e1;
      #pragma unroll
      for (int off = 32; off > 0; off >>= 1){
        sm0 += __shfl_xor(sm0, off, 64);
        sm1 += __shfl_xor(sm1, off, 64);
      }
      if (kp < 2){ sc[hkh][k0][m] = e0; sc[hkh][k1][m] = e1; }
      if (m == 0){
        float* pp = PART + (((size_t)b*NCH + ch)*8 + k0)*2;
        pp[0] = mx0; pp[1] = sm0;
        pp[2] = mx1; pp[3] = sm1;
      }
    }
    __syncthreads();
    {
      int n = tl >> 6, e = tl & 63;
      float pr = 0.f;
      for (int m = 0; m < 64; ++m) pr += sc[hkh][n][m] * mc[hkh][m][e];
      PREAD[(((size_t)b*NCH + ch)*4 + n)*64 + e] = pr;
    }
  }
}

// ---- PH_Dlite: read merge + write-side stats + wk save (+HF copy) (32 blocks) ----
// Parallel shuffle-tree stats, ef[] exp cache, XCD-affine batch mapping.
__global__ __launch_bounds__(256) void k_Dlite(
    const float* __restrict__ HPT, const float* __restrict__ PART,
    const float* __restrict__ PREAD, float* __restrict__ READT,
    float* __restrict__ RHIST, float* __restrict__ WST, float* __restrict__ WKS,
    const float* __restrict__ HHT, float* __restrict__ HF, int t)
{
  __shared__ float dn2[4];
  __shared__ float ef[4][32];
  const int bid = blockIdx.x, tid = threadIdx.x;
  const f4* HHT4 = (const f4*)HHT;
  int b = (bid & 7)*4 + (bid >> 3);   // XCD-affine: batch b's L2 home is XCD b>>2
  {
    // per-(kk,ch) stats: kk = tid>>5 in 0..7, ch = tid&31; 32-lane tree reduce
    int kk = tid >> 5, ch = tid & 31;
    const float* pp = PART + (((size_t)b*NCH + ch)*8 + kk)*2;
    float m0 = pp[0], s0 = pp[1];
    float mx = m0;
    #pragma unroll
    for (int off = 16; off > 0; off >>= 1)
      mx = fmaxf(mx, __shfl_xor(mx, off, 32));
    float d = s0 * __expf(m0 - mx);
    #pragma unroll
    for (int off = 16; off > 0; off >>= 1)
      d += __shfl_xor(d, off, 32);
    if (kk < 4){
      ef[kk][ch] = __expf(m0 - mx);     // same value as exp(cm - gm) in old merge
      if (ch == 0) dn2[kk] = d;
    } else if (ch == 0){
      float st = sigm(HPT[((kk-4)*129 + 128)*32 + b]);
      WST[b*8 + (kk-4)*2]     = mx;
      WST[b*8 + (kk-4)*2 + 1] = st / d;
    }
  }
  {
    // save raw write keys (HPT will be overwritten next step)
    int n = tid >> 6, e = tid & 63;
    WKS[(b*4 + n)*64 + e] = HPT[(n*129 + 64 + e)*32 + b];
  }
  __syncthreads();
  {
    int n = tid >> 6, e = tid & 63;
    const float* prp = PREAD + ((size_t)b*NCH*4 + n)*64 + e;
    float r = 0.f;
    #pragma unroll 8
    for (int ch = 0; ch < NCH; ++ch)
      r += prp[(size_t)ch*256] * ef[n][ch];
    r /= dn2[n];
    int k = n*64 + e;
    READT[(k>>2)*128 + b*4 + (k&3)] = r;
    RHIST[((size_t)t*64 + (k>>2))*128 + b*4 + (k&3)] = r;
  }
  if (t == T-1){
    int i = bid*256 + tid;       // 8192 slots, need 4096 f4
    if (i < 4096){
      int j4 = i & 127, bb = i >> 7;
      ((f4*)HF)[i] = HHT4[((size_t)(T-1)*128 + j4)*32 + bb];
    }
  }
}

// ---------------- final mem-update flush for t = T-1 (256 blocks) ----------------
__global__ __launch_bounds__(256) void k_flush(
    float* __restrict__ MEM, const float* __restrict__ SW,
    const float* __restrict__ WST, const float* __restrict__ WKS)
{
  __shared__ float gm[4], fac[4];
  __shared__ f4 wk4[4][16];
  __shared__ float ew[4][256];
  const int bid = blockIdx.x, tid = threadIdx.x;
  int xcd = bid & 7, t2 = bid >> 3;
  int b = xcd*4 + (t2 & 3), sub = t2 >> 2;     // 8 chunks of 256 rows
  if (tid < 4){ gm[tid] = WST[b*8 + tid*2]; fac[tid] = WST[b*8 + tid*2 + 1]; }
  if (tid < 64){
    int n = tid >> 4, e4 = tid & 15;
    wk4[n][e4] = ((const f4*)WKS)[(b*4 + n)*16 + e4];
  }
  __syncthreads();
  for (int idx = tid; idx < 1024; idx += 256){
    int n = idx >> 8, m = idx & 255;
    float s = SW[((size_t)b*4 + n)*MS + sub*256 + m];
    ew[n][m] = __expf(s - gm[n]) * fac[n];
  }
  __syncthreads();
  {
    int e4 = tid & 15, ms = tid >> 4;
    f4 k0 = wk4[0][e4], k1 = wk4[1][e4], k2 = wk4[2][e4], k3 = wk4[3][e4];
    #pragma unroll 2
    for (int it = 0; it < 16; ++it){
      int m = it*16 + ms;
      float w0 = ew[0][m], w1 = ew[1][m];
      float w2 = ew[2][m], w3 = ew[3][m];
      f4* p = (f4*)MEM + ((size_t)b*MS + sub*256 + m)*16 + e4;
      f4 v = *p;
      v += w0*k0 + w1*k1 + w2*k2 + w3*k3;
      *p = v;
    }
  }
}

// ---------------- final output GEMM (256 blocks) ----------------
__global__ __launch_bounds__(256) void k_out(
    const float* __restrict__ HHT, const float* __restrict__ RHIST,
    const float* __restrict__ WT_OUT, const float* __restrict__ b_out,
    float* __restrict__ out)
{
  __shared__ float A[16][260];
  const int bid = blockIdx.x, tid = threadIdx.x;
  const f4* HHT4 = (const f4*)HHT;
  const f4* RHIST4 = (const f4*)RHIST;
  const f4* W4 = (const f4*)WT_OUT;
  int nt = bid & 3, mt = bid >> 2;
  int rl = tid & 15, og = tid >> 4;
  int o = nt*64 + og*4, o4 = o >> 2;
  f4 a0 = {0.f,0.f,0.f,0.f}, a1 = a0, a2 = a0, a3 = a0;
  for (int kc = 0; kc < 3; ++kc){
    __syncthreads();
    for (int idx = tid; idx < 1024; idx += 256){
      int r = idx >> 6, k4 = idx & 63;
      int row = mt*16 + r;
      int bb = row >> 5, tt = row & 31;
      int kg4 = kc*64 + k4;
      f4 v = (kg4 < 128)
        ? HHT4[((size_t)tt*128 + kg4)*32 + bb]
        : RHIST4[((size_t)tt*64 + (kg4-128))*32 + bb];
      *(f4*)&A[r][k4*4] = v;
    }
    __syncthreads();
    const float* Ar = &A[rl][0];
    const f4* wp = W4 + (size_t)kc*256*64 + o4;
    #pragma unroll 2
    for (int k = 0; k < 256; k += 4){
      a0 += Ar[k]   * wp[(size_t)(k)*64];
      a1 += Ar[k+1] * wp[(size_t)(k+1)*64];
      a2 += Ar[k+2] * wp[(size_t)(k+2)*64];
      a3 += Ar[k+3] * wp[(size_t)(k+3)*64];
    }
  }
  int row = mt*16 + rl;
  f4 accv = (a0 + a1) + (a2 + a3);
  accv += *(const f4*)(b_out + o);
  *(f4*)(out + (size_t)row*O_DIM + o) = accv;
}

extern "C" void kernel_launch(void* const* d_in, const int* in_sizes, int n_in,
                              void* d_out, int out_size, void* d_ws, size_t ws_size,
                              hipStream_t stream)
{
  const float* x      = (const float*)d_in[0];
  const float* W_ih   = (const float*)d_in[1];
  const float* W_hh   = (const float*)d_in[2];
  const float* b_ih   = (const float*)d_in[3];
  const float* b_hh   = (const float*)d_in[4];
  const float* W_head = (const float*)d_in[5];
  const float* b_head = (const float*)d_in[6];
  const float* W_out  = (const float*)d_in[7];
  const float* b_out  = (const float*)d_in[8];

  float* out = (float*)d_out;
  float* MEM = out + B*T*O_DIM;
  float* HF  = MEM + (size_t)B*MS*HS;
  float* CF  = HF + B*H_DIM;

  float* ws      = (float*)d_ws;
  float* WT_HD2  = ws;                          // 520*512   = 266240
  float* WT_OUT  = WT_HD2 + 520*512;            // 768*256   = 196608
  float* XT      = WT_OUT + 768*256;            // 262144
  float* SW      = XT     + 262144;             // 32*4*2048 = 262144
  float* PART    = SW     + 262144;             // 32*32*8*2 = 16384
  float* PREAD   = PART   + 16384;              // 32*32*4*64= 262144
  float* HPT     = PREAD  + 262144;             // 520*32    = 16640
  float* READT   = HPT    + 16640;              // 256*32    = 8192
  float* HHT     = READT  + 8192;               // 32*512*32 = 524288
  float* RHIST   = HHT    + 524288;             // 32*256*32 = 262144
  float* WST     = RHIST  + 262144;             // 32*8      = 256
  float* WKS     = WST    + 256;                // 32*4*64   = 8192

  (void)hipMemsetAsync(MEM, 0, ((size_t)B*MS*HS + 2*B*H_DIM)*sizeof(float), stream);
  (void)hipMemsetAsync(READT, 0, (size_t)8192*sizeof(float), stream);

  k_ghead<<<1040, 256, 0, stream>>>(WT_HD2, W_head);
  k_transpose_t<<<dim3(8, 24), 256, 0, stream>>>(WT_OUT, W_out, 256, 768);
  k_xt<<<256, 256, 0, stream>>>((f4*)XT, x);

  for (int t = 0; t < T; ++t){
    k_A<<<256, 512, 0, stream>>>((const f4*)XT, W_ih, W_hh, b_ih, b_hh,
                                 (const f4*)READT, HHT, CF, t);
    k_B<<<260, 256, 0, stream>>>(HHT, WT_HD2, b_head, HPT, t);
    k_CD<<<256, 512, 0, stream>>>(MEM, HPT, SW, PART, PREAD, WST, WKS, t);
    k_Dlite<<<32, 256, 0, stream>>>(HPT, PART, PREAD, READT, RHIST, WST, WKS,
                                    HHT, HF, t);
  }
  k_flush<<<256, 256, 0, stream>>>(MEM, SW, WST, WKS);
  k_out<<<256, 256, 0, stream>>>(HHT, RHIST, WT_OUT, b_out, out);
}

// Round 11
// 1115.532 us; speedup vs baseline: 1.1574x; 1.0623x over previous
//
#include <hip/hip_runtime.h>
#include <math.h>

#define B 32
#define T 32
#define O_DIM 256
#define H_DIM 512
#define HS 64
#define MS 2048
#define NCOL 516
#define NCH 32          // 64-row softmax chunks

typedef __attribute__((ext_vector_type(4))) float f4;

__device__ __forceinline__ float sigm(float x){ return 1.0f/(1.0f+__expf(-x)); }
__device__ __forceinline__ float hsum(f4 v){ return (v.x + v.y) + (v.z + v.w); }

// ---------------- prep kernels ----------------
__global__ __launch_bounds__(256) void k_transpose_t(float* __restrict__ dst,
                                                     const float* __restrict__ src,
                                                     int N, int K){
  __shared__ float tile[32][33];
  int jb = blockIdx.x*32, kb = blockIdx.y*32;
  int tj = threadIdx.x & 31, tk = threadIdx.x >> 5;
  #pragma unroll
  for (int p = 0; p < 4; ++p){
    int j = jb + tk + p*8, k = kb + tj;
    if (j < N && k < K) tile[tk + p*8][tj] = src[j*K + k];
  }
  __syncthreads();
  #pragma unroll
  for (int p = 0; p < 4; ++p){
    int k = kb + tk + p*8, j = jb + tj;
    if (j < N && k < K) dst[k*N + j] = tile[tj][tk + p*8];
  }
}

__global__ __launch_bounds__(256) void k_ghead(float* __restrict__ dst,
                                               const float* __restrict__ W_head){
  int idx = blockIdx.x*256 + threadIdx.x;     // col*512 + k
  if (idx >= 520*512) return;
  int col = idx >> 9, k = idx & 511;
  float v = 0.f;
  if (col < NCOL){ int n = col/129, c = col%129; v = W_head[((size_t)n*2115 + c)*512 + k]; }
  dst[idx] = v;
}

__global__ __launch_bounds__(256) void k_xt(f4* __restrict__ XT4,
                                            const float* __restrict__ x){
  int idx = blockIdx.x*256 + threadIdx.x;     // t*2048 + k4*32 + b
  int b = idx & 31, k4 = (idx >> 5) & 63, t = idx >> 11;
  XT4[idx] = ((const f4*)x)[(size_t)(b*T + t)*64 + k4];
}

// ---- PH_AU: gates GEMM + LSTM (blocks 0..255) ∥ deferred mem-update (256..511) ----
// k_A part: k-split, waves 0-3 do x+read half; waves 4-7 do h half (R10 verbatim).
// update part: k_flush body (bit-identical per-element expression), applies the
// step t-1 memory write — its inputs (WST/WKS/SW) are ready before this launch.
__global__ __launch_bounds__(512) void k_AU(
    const f4* __restrict__ XT4, const float* __restrict__ W_ih,
    const float* __restrict__ W_hh, const float* __restrict__ b_ih,
    const float* __restrict__ b_hh, const f4* __restrict__ READT4,
    float* __restrict__ HHT, float* __restrict__ CF,
    float* __restrict__ MEM, const float* __restrict__ SW,
    const float* __restrict__ WST, const float* __restrict__ WKS, int t)
{
  __shared__ f4 WS[8*256];         // 32 KB (k_A branch)
  __shared__ float glp[2][8][33];  // per-khalf partials
  __shared__ float gm[4], fac[4];  // update branch
  __shared__ f4 wk4[4][16];
  __shared__ float ew[4][256];
  const int bid = blockIdx.x, tid = threadIdx.x;
  const f4* HHT4 = (const f4*)HHT;

  if (bid < 256){
    for (int idx = tid; idx < 2048; idx += 512){
      int rsub = idx >> 8, q = idx & 255;
      int gate = rsub & 3, jj = (rsub >> 2) & 1;
      int row = gate*512 + bid*2 + jj;
      WS[idx] = (q < 128) ? ((const f4*)W_ih)[(size_t)row*128 + q]
                          : ((const f4*)W_hh)[(size_t)row*128 + (q - 128)];
    }
    __syncthreads();
    {
      int b = tid & 31, rsub = (tid >> 5) & 7, khalf = tid >> 8;
      const f4* w = WS + rsub*256;
      f4 a0 = {0.f,0.f,0.f,0.f}, a1 = {0.f,0.f,0.f,0.f};
      if (khalf == 0){
        const f4* xt4 = XT4 + (size_t)t*2048;
        #pragma unroll 4
        for (int k4 = 0; k4 < 64; k4 += 2){
          a0 += w[k4]     * xt4[k4*32 + b];
          a1 += w[k4+1]   * xt4[(k4+1)*32 + b];
        }
        #pragma unroll 4
        for (int k4 = 0; k4 < 64; k4 += 2){
          a0 += w[64+k4]   * READT4[k4*32 + b];
          a1 += w[64+k4+1] * READT4[(k4+1)*32 + b];
        }
      } else if (t > 0){
        const f4* ht4 = HHT4 + (size_t)(t-1)*4096;
        #pragma unroll 4
        for (int k4 = 0; k4 < 128; k4 += 2){
          a0 += w[128+k4]   * ht4[k4*32 + b];
          a1 += w[128+k4+1] * ht4[(k4+1)*32 + b];
        }
      }
      glp[khalf][rsub][b] = hsum(a0 + a1);
    }
    __syncthreads();
    if (tid < 64){
      int b2 = tid & 31, jj2 = tid >> 5;
      int j2 = bid*2 + jj2;
      int r0 = 0*512 + j2, r1 = 1*512 + j2, r2 = 2*512 + j2, r3 = 3*512 + j2;
      float gi = glp[0][jj2*4+0][b2] + glp[1][jj2*4+0][b2] + b_ih[r0] + b_hh[r0];
      float gf = glp[0][jj2*4+1][b2] + glp[1][jj2*4+1][b2] + b_ih[r1] + b_hh[r1];
      float gg = glp[0][jj2*4+2][b2] + glp[1][jj2*4+2][b2] + b_ih[r2] + b_hh[r2];
      float go = glp[0][jj2*4+3][b2] + glp[1][jj2*4+3][b2] + b_ih[r3] + b_hh[r3];
      float c = sigm(gf)*CF[b2*512+j2] + sigm(gi)*tanhf(gg);
      float h = sigm(go)*tanhf(c);
      CF[b2*512+j2] = c;
      HHT[((size_t)t*128 + (j2>>2))*128 + b2*4 + (j2&3)] = h;
    }
  } else {
    // -------- deferred mem-update for step t-1 (k_flush body, 512 thr) --------
    if (t == 0) return;
    int i = bid - 256;
    int xcd = i & 7, r2 = i >> 3;
    int b = xcd*4 + (r2 & 3), sub = r2 >> 2;     // 8 chunks of 256 rows
    if (tid < 4){ gm[tid] = WST[b*8 + tid*2]; fac[tid] = WST[b*8 + tid*2 + 1]; }
    if (tid < 64){
      int n = tid >> 4, e4 = tid & 15;
      wk4[n][e4] = ((const f4*)WKS)[(b*4 + n)*16 + e4];
    }
    __syncthreads();
    for (int idx = tid; idx < 1024; idx += 512){
      int n = idx >> 8, m = idx & 255;
      float s = SW[((size_t)b*4 + n)*MS + sub*256 + m];
      ew[n][m] = __expf(s - gm[n]) * fac[n];
    }
    __syncthreads();
    {
      int e4 = tid & 15, ms = tid >> 4;          // ms in 0..31
      f4 k0 = wk4[0][e4], k1 = wk4[1][e4], k2 = wk4[2][e4], k3 = wk4[3][e4];
      #pragma unroll 2
      for (int it = 0; it < 8; ++it){
        int m = it*32 + ms;
        float w0 = ew[0][m], w1 = ew[1][m];
        float w2 = ew[2][m], w3 = ew[3][m];
        f4* p = (f4*)MEM + ((size_t)b*MS + sub*256 + m)*16 + e4;
        f4 v = *p;
        v += w0*k0 + w1*k1 + w2*k2 + w3*k3;
        *p = v;
      }
    }
  }
}

// ---------------- PH_B: head projection (260 blocks, 2 cols, 4-way k-split) ----
__global__ __launch_bounds__(256) void k_B(
    const float* __restrict__ HHT, const float* __restrict__ WT_HD2,
    const float* __restrict__ b_head, float* __restrict__ HPT, int t)
{
  __shared__ float red[256];
  const int bid = blockIdx.x, tid = threadIdx.x;
  const f4* HHT4 = (const f4*)HHT;
  int b = tid & 31, cs = (tid>>5)&1, kq = tid>>6;   // kq in 0..3
  int col = bid*2 + cs;
  const f4* hT4 = HHT4 + (size_t)t*4096 + kq*1024;  // quarter of k (32 f4)
  const f4* w4  = (const f4*)(WT_HD2 + (size_t)col*512) + kq*32;
  f4 acc4 = {0.f, 0.f, 0.f, 0.f};
  #pragma unroll 4
  for (int k4 = 0; k4 < 32; ++k4)
    acc4 += w4[k4] * hT4[k4*32 + b];
  red[tid] = hsum(acc4);
  __syncthreads();
  if (kq == 0){
    float v = red[tid] + red[tid + 64] + red[tid + 128] + red[tid + 192];
    if (col < NCOL){ int n = col/129, c = col%129; v += b_head[n*2115 + c]; }
    HPT[col*32 + b] = v;
  }
}

// ---- PH_CD: scores + wave-softmax + partial reads (mem-update hoisted to k_AU) ----
// 256 blocks x 512 thr: half hkh = tid>>8 handles chunks ch8*4 + hkh*2 + {0,1}.
__global__ __launch_bounds__(512) void k_CD(
    const float* __restrict__ MEM, const float* __restrict__ HPT,
    float* __restrict__ SW, float* __restrict__ PART, float* __restrict__ PREAD,
    int t)
{
  __shared__ float keys[8][64];
  __shared__ float mc[2][64][68];
  __shared__ float sc[2][4][64];
  const int bid = blockIdx.x, tid = threadIdx.x;
  const f4* MEM4 = (const f4*)MEM;
  int xcd = bid & 7, t2 = bid >> 3;
  int b = xcd*4 + (t2 & 3), ch8 = t2 >> 2;
  int hkh = tid >> 8, tl = tid & 255;       // half index, local tid
  if (tid < 512){
    int kk = tid >> 6, e = tid & 63;
    int n = kk & 3;
    int c = (kk >= 4) ? (64 + e) : e;
    keys[kk][e] = HPT[(n*129 + c)*32 + b];
  }
  for (int sub = 0; sub < 2; ++sub){
    int ch = ch8*4 + hkh*2 + sub;
    __syncthreads();
    for (int idx = tl; idx < 64*16; idx += 256){
      int m = idx >> 4, e4 = idx & 15;
      ((f4*)&mc[hkh][m][0])[e4] = MEM4[((size_t)b*MS + ch*64 + m)*16 + e4];
    }
    __syncthreads();
    {
      int m = tl & 63, kp = tl >> 6;    // wave kp (within half) holds rows 2kp,2kp+1
      const f4* mrow4 = (const f4*)&mc[hkh][m][0];
      int k0 = kp*2, k1 = kp*2+1;
      f4 s0v = {0.f,0.f,0.f,0.f}, s1v = {0.f,0.f,0.f,0.f};
      #pragma unroll 4
      for (int e4 = 0; e4 < 16; ++e4){
        f4 mv = mrow4[e4];
        s0v += mv * (*(const f4*)&keys[k0][e4*4]);
        s1v += mv * (*(const f4*)&keys[k1][e4*4]);
      }
      float s0 = hsum(s0v)*0.125f, s1 = hsum(s1v)*0.125f;
      if (kp >= 2){
        float* swp = SW + ((size_t)b*4 + (k0-4))*MS + ch*64 + m;
        swp[0] = s0; swp[MS] = s1;
      }
      // in-wave softmax: max (exact) then exp then sum, rows span the 64 lanes
      float mx0 = s0, mx1 = s1;
      #pragma unroll
      for (int off = 32; off > 0; off >>= 1){
        mx0 = fmaxf(mx0, __shfl_xor(mx0, off, 64));
        mx1 = fmaxf(mx1, __shfl_xor(mx1, off, 64));
      }
      float e0 = __expf(s0 - mx0), e1 = __expf(s1 - mx1);
      float sm0 = e0, sm1 = e1;
      #pragma unroll
      for (int off = 32; off > 0; off >>= 1){
        sm0 += __shfl_xor(sm0, off, 64);
        sm1 += __shfl_xor(sm1, off, 64);
      }
      if (kp < 2){ sc[hkh][k0][m] = e0; sc[hkh][k1][m] = e1; }
      if (m == 0){
        float* pp = PART + (((size_t)b*NCH + ch)*8 + k0)*2;
        pp[0] = mx0; pp[1] = sm0;
        pp[2] = mx1; pp[3] = sm1;
      }
    }
    __syncthreads();
    {
      int n = tl >> 6, e = tl & 63;
      float pr = 0.f;
      for (int m = 0; m < 64; ++m) pr += sc[hkh][n][m] * mc[hkh][m][e];
      PREAD[(((size_t)b*NCH + ch)*4 + n)*64 + e] = pr;
    }
  }
}

// ---- PH_Dlite: read merge + write-side stats + wk save (+HF copy) (32 blocks) ----
// Parallel shuffle-tree stats, ef[] exp cache, XCD-affine batch mapping.
__global__ __launch_bounds__(256) void k_Dlite(
    const float* __restrict__ HPT, const float* __restrict__ PART,
    const float* __restrict__ PREAD, float* __restrict__ READT,
    float* __restrict__ RHIST, float* __restrict__ WST, float* __restrict__ WKS,
    const float* __restrict__ HHT, float* __restrict__ HF, int t)
{
  __shared__ float dn2[4];
  __shared__ float ef[4][32];
  const int bid = blockIdx.x, tid = threadIdx.x;
  const f4* HHT4 = (const f4*)HHT;
  int b = (bid & 7)*4 + (bid >> 3);   // XCD-affine: batch b's L2 home is XCD b>>2
  {
    // per-(kk,ch) stats: kk = tid>>5 in 0..7, ch = tid&31; 32-lane tree reduce
    int kk = tid >> 5, ch = tid & 31;
    const float* pp = PART + (((size_t)b*NCH + ch)*8 + kk)*2;
    float m0 = pp[0], s0 = pp[1];
    float mx = m0;
    #pragma unroll
    for (int off = 16; off > 0; off >>= 1)
      mx = fmaxf(mx, __shfl_xor(mx, off, 32));
    float d = s0 * __expf(m0 - mx);
    #pragma unroll
    for (int off = 16; off > 0; off >>= 1)
      d += __shfl_xor(d, off, 32);
    if (kk < 4){
      ef[kk][ch] = __expf(m0 - mx);     // same value as exp(cm - gm) in old merge
      if (ch == 0) dn2[kk] = d;
    } else if (ch == 0){
      float st = sigm(HPT[((kk-4)*129 + 128)*32 + b]);
      WST[b*8 + (kk-4)*2]     = mx;
      WST[b*8 + (kk-4)*2 + 1] = st / d;
    }
  }
  {
    // save raw write keys (HPT will be overwritten next step)
    int n = tid >> 6, e = tid & 63;
    WKS[(b*4 + n)*64 + e] = HPT[(n*129 + 64 + e)*32 + b];
  }
  __syncthreads();
  {
    int n = tid >> 6, e = tid & 63;
    const float* prp = PREAD + ((size_t)b*NCH*4 + n)*64 + e;
    float r = 0.f;
    #pragma unroll 8
    for (int ch = 0; ch < NCH; ++ch)
      r += prp[(size_t)ch*256] * ef[n][ch];
    r /= dn2[n];
    int k = n*64 + e;
    READT[(k>>2)*128 + b*4 + (k&3)] = r;
    RHIST[((size_t)t*64 + (k>>2))*128 + b*4 + (k&3)] = r;
  }
  if (t == T-1){
    int i = bid*256 + tid;       // 8192 slots, need 4096 f4
    if (i < 4096){
      int j4 = i & 127, bb = i >> 7;
      ((f4*)HF)[i] = HHT4[((size_t)(T-1)*128 + j4)*32 + bb];
    }
  }
}

// ---------------- final mem-update flush for t = T-1 (256 blocks) ----------------
__global__ __launch_bounds__(256) void k_flush(
    float* __restrict__ MEM, const float* __restrict__ SW,
    const float* __restrict__ WST, const float* __restrict__ WKS)
{
  __shared__ float gm[4], fac[4];
  __shared__ f4 wk4[4][16];
  __shared__ float ew[4][256];
  const int bid = blockIdx.x, tid = threadIdx.x;
  int xcd = bid & 7, t2 = bid >> 3;
  int b = xcd*4 + (t2 & 3), sub = t2 >> 2;     // 8 chunks of 256 rows
  if (tid < 4){ gm[tid] = WST[b*8 + tid*2]; fac[tid] = WST[b*8 + tid*2 + 1]; }
  if (tid < 64){
    int n = tid >> 4, e4 = tid & 15;
    wk4[n][e4] = ((const f4*)WKS)[(b*4 + n)*16 + e4];
  }
  __syncthreads();
  for (int idx = tid; idx < 1024; idx += 256){
    int n = idx >> 8, m = idx & 255;
    float s = SW[((size_t)b*4 + n)*MS + sub*256 + m];
    ew[n][m] = __expf(s - gm[n]) * fac[n];
  }
  __syncthreads();
  {
    int e4 = tid & 15, ms = tid >> 4;
    f4 k0 = wk4[0][e4], k1 = wk4[1][e4], k2 = wk4[2][e4], k3 = wk4[3][e4];
    #pragma unroll 2
    for (int it = 0; it < 16; ++it){
      int m = it*16 + ms;
      float w0 = ew[0][m], w1 = ew[1][m];
      float w2 = ew[2][m], w3 = ew[3][m];
      f4* p = (f4*)MEM + ((size_t)b*MS + sub*256 + m)*16 + e4;
      f4 v = *p;
      v += w0*k0 + w1*k1 + w2*k2 + w3*k3;
      *p = v;
    }
  }
}

// ---------------- final output GEMM (256 blocks) ----------------
__global__ __launch_bounds__(256) void k_out(
    const float* __restrict__ HHT, const float* __restrict__ RHIST,
    const float* __restrict__ WT_OUT, const float* __restrict__ b_out,
    float* __restrict__ out)
{
  __shared__ float A[16][260];
  const int bid = blockIdx.x, tid = threadIdx.x;
  const f4* HHT4 = (const f4*)HHT;
  const f4* RHIST4 = (const f4*)RHIST;
  const f4* W4 = (const f4*)WT_OUT;
  int nt = bid & 3, mt = bid >> 2;
  int rl = tid & 15, og = tid >> 4;
  int o = nt*64 + og*4, o4 = o >> 2;
  f4 a0 = {0.f,0.f,0.f,0.f}, a1 = a0, a2 = a0, a3 = a0;
  for (int kc = 0; kc < 3; ++kc){
    __syncthreads();
    for (int idx = tid; idx < 1024; idx += 256){
      int r = idx >> 6, k4 = idx & 63;
      int row = mt*16 + r;
      int bb = row >> 5, tt = row & 31;
      int kg4 = kc*64 + k4;
      f4 v = (kg4 < 128)
        ? HHT4[((size_t)tt*128 + kg4)*32 + bb]
        : RHIST4[((size_t)tt*64 + (kg4-128))*32 + bb];
      *(f4*)&A[r][k4*4] = v;
    }
    __syncthreads();
    const float* Ar = &A[rl][0];
    const f4* wp = W4 + (size_t)kc*256*64 + o4;
    #pragma unroll 2
    for (int k = 0; k < 256; k += 4){
      a0 += Ar[k]   * wp[(size_t)(k)*64];
      a1 += Ar[k+1] * wp[(size_t)(k+1)*64];
      a2 += Ar[k+2] * wp[(size_t)(k+2)*64];
      a3 += Ar[k+3] * wp[(size_t)(k+3)*64];
    }
  }
  int row = mt*16 + rl;
  f4 accv = (a0 + a1) + (a2 + a3);
  accv += *(const f4*)(b_out + o);
  *(f4*)(out + (size_t)row*O_DIM + o) = accv;
}

extern "C" void kernel_launch(void* const* d_in, const int* in_sizes, int n_in,
                              void* d_out, int out_size, void* d_ws, size_t ws_size,
                              hipStream_t stream)
{
  const float* x      = (const float*)d_in[0];
  const float* W_ih   = (const float*)d_in[1];
  const float* W_hh   = (const float*)d_in[2];
  const float* b_ih   = (const float*)d_in[3];
  const float* b_hh   = (const float*)d_in[4];
  const float* W_head = (const float*)d_in[5];
  const float* b_head = (const float*)d_in[6];
  const float* W_out  = (const float*)d_in[7];
  const float* b_out  = (const float*)d_in[8];

  float* out = (float*)d_out;
  float* MEM = out + B*T*O_DIM;
  float* HF  = MEM + (size_t)B*MS*HS;
  float* CF  = HF + B*H_DIM;

  float* ws      = (float*)d_ws;
  float* WT_HD2  = ws;                          // 520*512   = 266240
  float* WT_OUT  = WT_HD2 + 520*512;            // 768*256   = 196608
  float* XT      = WT_OUT + 768*256;            // 262144
  float* SW      = XT     + 262144;             // 32*4*2048 = 262144
  float* PART    = SW     + 262144;             // 32*32*8*2 = 16384
  float* PREAD   = PART   + 16384;              // 32*32*4*64= 262144
  float* HPT     = PREAD  + 262144;             // 520*32    = 16640
  float* READT   = HPT    + 16640;              // 256*32    = 8192
  float* HHT     = READT  + 8192;               // 32*512*32 = 524288
  float* RHIST   = HHT    + 524288;             // 32*256*32 = 262144
  float* WST     = RHIST  + 262144;             // 32*8      = 256
  float* WKS     = WST    + 256;                // 32*4*64   = 8192

  (void)hipMemsetAsync(MEM, 0, ((size_t)B*MS*HS + 2*B*H_DIM)*sizeof(float), stream);
  (void)hipMemsetAsync(READT, 0, (size_t)8192*sizeof(float), stream);

  k_ghead<<<1040, 256, 0, stream>>>(WT_HD2, W_head);
  k_transpose_t<<<dim3(8, 24), 256, 0, stream>>>(WT_OUT, W_out, 256, 768);
  k_xt<<<256, 256, 0, stream>>>((f4*)XT, x);

  for (int t = 0; t < T; ++t){
    k_AU<<<512, 512, 0, stream>>>((const f4*)XT, W_ih, W_hh, b_ih, b_hh,
                                  (const f4*)READT, HHT, CF,
                                  MEM, SW, WST, WKS, t);
    k_B<<<260, 256, 0, stream>>>(HHT, WT_HD2, b_head, HPT, t);
    k_CD<<<256, 512, 0, stream>>>(MEM, HPT, SW, PART, PREAD, t);
    k_Dlite<<<32, 256, 0, stream>>>(HPT, PART, PREAD, READT, RHIST, WST, WKS,
                                    HHT, HF, t);
  }
  k_flush<<<256, 256, 0, stream>>>(MEM, SW, WST, WKS);
  k_out<<<256, 256, 0, stream>>>(HHT, RHIST, WT_OUT, b_out, out);
}